// Round 15
// baseline (188.437 us; speedup 1.0000x reference)
//
#include <hip/hip_runtime.h>
#include <cstdint>

// ---- types ----
typedef __bf16 bf16x8 __attribute__((ext_vector_type(8)));
typedef float  f32x4  __attribute__((ext_vector_type(4)));
typedef float  f32x16 __attribute__((ext_vector_type(16)));
typedef float  float8v __attribute__((ext_vector_type(8)));
typedef unsigned short ushort8v __attribute__((ext_vector_type(8)));
typedef unsigned short ushort4v __attribute__((ext_vector_type(4)));
typedef unsigned int   uint4v   __attribute__((ext_vector_type(4)));

__device__ __forceinline__ unsigned short f2b(float f) {
  uint32_t u = __builtin_bit_cast(uint32_t, f);
  u += 0x7FFFu + ((u >> 16) & 1u);     // round-to-nearest-even
  return (unsigned short)(u >> 16);
}
__device__ __forceinline__ float b2f(unsigned short h) {
  uint32_t u = ((uint32_t)h) << 16;
  return __builtin_bit_cast(float, u);
}
__device__ __forceinline__ unsigned int cvtpk(float lo, float hi_) {
  unsigned int r;
  asm("v_cvt_pk_bf16_f32 %0, %1, %2" : "=v"(r) : "v"(lo), "v"(hi_));
  return r;
}

__device__ __forceinline__ void async16(const void* g, void* l) {
  __builtin_amdgcn_global_load_lds(
      (const __attribute__((address_space(1))) void*)g,
      (__attribute__((address_space(3))) void*)l, 16, 0, 0);
}

// s_waitcnt immediates (gfx9 encoding): vmcnt[3:0]|[15:14], expcnt[6:4], lgkmcnt[11:8]
#define WAITVM(N)  __builtin_amdgcn_s_waitcnt(0x0F70 | ((N) & 15))

// ---- fused fp32 -> bf16 convert, 5 segments in one launch ----
struct CvtArgs {
  const float* src[5];
  unsigned short* dst[5];
  long n[5];
};
__global__ void cvt5_kernel(CvtArgs a) {
  long base = (long)blockIdx.x * blockDim.x + threadIdx.x;
  long gstride = (long)gridDim.x * blockDim.x;
#pragma unroll 1
  for (int sg = 0; sg < 5; ++sg) {
    const float* s = a.src[sg];
    unsigned short* d = a.dst[sg];
    long n8 = a.n[sg] >> 3;
    for (long i = base; i < n8; i += gstride) {
      float8v f = *(const float8v*)(s + i * 8);
      ushort8v o;
#pragma unroll
      for (int j = 0; j < 8; ++j) o[j] = f2b(f[j]);
      *(ushort8v*)(d + i * 8) = o;
    }
  }
}

// ---- 2-blocks/CU GEMM: C[M][N] = A[M][K] * W[N][K]^T, K=2048, BM=128 ----
template<bool F32OUT, int BN>
__global__ __launch_bounds__(512, 4)
void gemmLT(const unsigned short* __restrict__ Ag, const unsigned short* __restrict__ Wg,
            void* __restrict__ Cp) {
  constexpr int K = 2048;
  constexpr int NF = BN / 64;
  constexpr int BL = NF;
  constexpr int VMS = 1 + BL;
  constexpr int ASLOT = 8192;
  constexpr int BSLOT = BN * 128;
  constexpr int N = 16 * BN;

  extern __shared__ char lds_c[];

  const int tid = threadIdx.x;
  const int wave = tid >> 6, lane = tid & 63;
  const int wm = wave >> 2, wn = wave & 3;
  const int lr = lane & 15, lg = lane >> 4;

  const int flat = blockIdx.y * 16 + blockIdx.x;
  const int swz = (flat & 7) * 64 + (flat >> 3);
  const int m0 = (swz >> 4) * 128, n0 = (swz & 15) * BN;

  const int laneSw = (lr >> 1) * 128 + (((((lr & 1) << 2) | lg) ^ (lr >> 1)) << 4);
  const int aoff = wm * 4096 + laneSw;

  int bByte[NF], bR7[NF];
#pragma unroll
  for (int ni = 0; ni < NF; ++ni) {
    int row = wn * (NF * 16) + ni * 16 + lr;
    bByte[ni] = row * 128;
    bR7[ni] = row & 7;
  }

  f32x4 acc[4][NF] = {};
  bf16x8 af[2], bf[NF];

  auto stA = [&](int slot, int s) {
    char* sl = lds_c + slot * ASLOT;
    const int kc = s * 32;
    int q = tid * 16;
    int R = q >> 7, g2L = ((q >> 4) & 7) ^ (R & 7);
    int row = R * 2 + (g2L >> 2), kg = g2L & 3;
    async16(Ag + (size_t)(m0 + row) * K + kc + kg * 8, sl + q);
  };
  auto stB = [&](int slot, int T) {
    char* sl = lds_c + 4 * ASLOT + slot * BSLOT;
    const int kc = T * 64;
#pragma unroll
    for (int j = 0; j < BL; ++j) {
      int q = (tid + 512 * j) * 16;
      int row = q >> 7, c = (q >> 4) & 7;
      async16(Wg + (size_t)(n0 + row) * K + kc + ((c ^ (row & 7)) * 8), sl + q);
    }
  };

#define PH(SA, SB, MH, KH, RDB, STG, VM)                                      \
  {                                                                           \
    const char* As_ = lds_c + (SA) * ASLOT;                                   \
    _Pragma("unroll") for (int mi = 0; mi < 2; ++mi)                          \
      af[mi] = *(const bf16x8*)(As_ + aoff + ((MH) * 2 + mi) * 1024);         \
    if (RDB) {                                                                \
      const char* Bs_ = lds_c + 4 * ASLOT + (SB) * BSLOT;                     \
      _Pragma("unroll") for (int ni = 0; ni < NF; ++ni)                       \
        bf[ni] = *(const bf16x8*)(Bs_ + bByte[ni] +                           \
                                  (((((KH) << 2) | lg) ^ bR7[ni]) << 4));     \
    }                                                                         \
    STG;                                                                      \
    if ((VM) >= 0) WAITVM(VM);                                                \
    __builtin_amdgcn_s_barrier();                                             \
    __builtin_amdgcn_s_setprio(1);                                            \
    _Pragma("unroll") for (int mi = 0; mi < 2; ++mi)                          \
      _Pragma("unroll") for (int ni = 0; ni < NF; ++ni)                       \
        acc[(MH) * 2 + mi][ni] = __builtin_amdgcn_mfma_f32_16x16x32_bf16(     \
            af[mi], bf[ni], acc[(MH) * 2 + mi][ni], 0, 0, 0);                 \
    __builtin_amdgcn_s_setprio(0);                                            \
    __builtin_amdgcn_s_barrier();                                             \
  }

  stB(0, 0); stA(0, 0); stA(1, 1); stB(1, 1); stA(2, 2);
  WAITVM(VMS);
  __builtin_amdgcn_s_barrier();

  for (int t2 = 0; t2 < 30; t2 += 2) {
    PH(0, 0, 0, 0, true,  stA(3, 2 * t2 + 3), -1);
    PH(0, 0, 1, 0, false, (void)0, -1);
    PH(1, 0, 0, 1, true,  stA(0, 2 * t2 + 4), -1);
    PH(1, 0, 1, 1, false, stB(0, t2 + 2), VMS);
    PH(2, 1, 0, 0, true,  stA(1, 2 * t2 + 5), -1);
    PH(2, 1, 1, 0, false, (void)0, -1);
    PH(3, 1, 0, 1, true,  stA(2, 2 * t2 + 6), -1);
    PH(3, 1, 1, 1, false, stB(1, t2 + 3), VMS);
  }
  PH(0, 0, 0, 0, true,  stA(3, 63), -1);
  PH(0, 0, 1, 0, false, (void)0, -1);
  PH(1, 0, 0, 1, true,  (void)0, -1);
  PH(1, 0, 1, 1, false, (void)0, 0);
  PH(2, 1, 0, 0, true,  (void)0, -1);
  PH(2, 1, 1, 0, false, (void)0, -1);
  PH(3, 1, 0, 1, true,  (void)0, -1);
  PH(3, 1, 1, 1, false, (void)0, -1);
#undef PH

#pragma unroll
  for (int mig = 0; mig < 4; ++mig) {
#pragma unroll
    for (int j = 0; j < 4; ++j) {
      int row = m0 + wm * 64 + mig * 16 + lg * 4 + j;
#pragma unroll
      for (int ni = 0; ni < NF; ++ni) {
        int col = n0 + wn * (NF * 16) + ni * 16 + lr;
        float v = acc[mig][ni][j];
        if (F32OUT) ((float*)Cp)[(size_t)row * N + col] = v;
        else        ((unsigned short*)Cp)[(size_t)row * N + col] = f2b(v);
      }
    }
  }
}

// ---- fused K-RoPE (in place) + V transpose -> vt[b][kvh][d=64][t=1024] ----
__global__ __launch_bounds__(256)
void ropekv_kernel(unsigned short* __restrict__ qkv,
                   const float* __restrict__ cosb, const float* __restrict__ sinb,
                   unsigned short* __restrict__ vt) {
  const int tt0 = blockIdx.x * 64;
  const int kvh = blockIdx.y;
  const int b   = blockIdx.z;
  const int tid = threadIdx.x;

  {
    int r = tid >> 2, c0 = (tid & 3) * 16;
    int t = tt0 + r;
    unsigned short* kp = qkv + (size_t)(b * 1024 + t) * 3072 + 2048 + kvh * 64 + c0;
    const float* cb = cosb + t * 32 + c0 / 2;
    const float* sb = sinb + t * 32 + c0 / 2;
    ushort8v x0 = *(const ushort8v*)kp;
    ushort8v x1 = *(const ushort8v*)(kp + 8);
    float8v c = *(const float8v*)cb;
    float8v s = *(const float8v*)sb;
    ushort8v o0, o1;
#pragma unroll
    for (int j = 0; j < 4; ++j) {
      float xr = b2f(x0[2 * j]), xi = b2f(x0[2 * j + 1]);
      o0[2 * j]     = f2b(xr * c[j] - xi * s[j]);
      o0[2 * j + 1] = f2b(xr * s[j] + xi * c[j]);
    }
#pragma unroll
    for (int j = 0; j < 4; ++j) {
      float xr = b2f(x1[2 * j]), xi = b2f(x1[2 * j + 1]);
      o1[2 * j]     = f2b(xr * c[4 + j] - xi * s[4 + j]);
      o1[2 * j + 1] = f2b(xr * s[4 + j] + xi * c[4 + j]);
    }
    *(ushort8v*)kp = o0;
    *(ushort8v*)(kp + 8) = o1;
  }

  __shared__ unsigned short lT[64 * 68];
#pragma unroll
  for (int i = 0; i < 2; ++i) {
    int r = i * 32 + (tid >> 3), c = (tid & 7) * 8;
    const unsigned short* src = qkv + (size_t)(b * 1024 + tt0 + r) * 3072 + 2560 + kvh * 64 + c;
    ushort8v v = *(const ushort8v*)src;
    ushort4v a, b4;
#pragma unroll
    for (int j = 0; j < 4; ++j) { a[j] = v[j]; b4[j] = v[j + 4]; }
    *(ushort4v*)&lT[r * 68 + c]     = a;
    *(ushort4v*)&lT[r * 68 + c + 4] = b4;
  }
  __syncthreads();
#pragma unroll
  for (int i = 0; i < 2; ++i) {
    int d = tid & 63;
    int tt = i * 4 + (tid >> 6);
    ushort8v o;
#pragma unroll
    for (int j = 0; j < 8; ++j) o[j] = lT[(tt * 8 + j) * 68 + d];
    *(ushort8v*)&vt[((size_t)((b * 8 + kvh) * 64 + d)) * 1024 + tt0 + tt * 8] = o;
  }
}

// ---- flash attention: ONE q-tile per block, 4 waves = 4 heads, KVBLK=64 ----
// grid (32,8,4) XCD-swizzled, 256 threads. All waves share nt = qt/2+1 ->
// zero intra-block wave idling; 1024 variable-length blocks pack onto 256 CUs
// at 5 blocks/CU (LDS 32KB x 5 = 160KB), refilled as short blocks retire.
__global__ __launch_bounds__(256, 5)
void attn_kernel(const unsigned short* __restrict__ qkv, const unsigned short* __restrict__ vt,
                 const float* __restrict__ cosb, const float* __restrict__ sinb,
                 unsigned short* __restrict__ ob) {
  // chunked XCD swizzle over 1024 blocks (cpx=128): 4 (b,kvh) streams per XCD
  const int flat = (blockIdx.z * 8 + blockIdx.y) * 32 + blockIdx.x;
  const int swzb = (flat & 7) * 128 + (flat >> 3);
  const int qt = swzb & 31, kvh = (swzb >> 5) & 7, b = swzb >> 8;

  const int tid = threadIdx.x, wave = tid >> 6, lane = tid & 63;
  const int l31 = lane & 31, hi = lane >> 5;
  const int h = kvh * 4 + wave;

  const int q0 = qt * 32;
  const int nt = qt / 2 + 1;                         // KVBLK=64 tiles

  __shared__ unsigned short lK[2][64 * 64];
  __shared__ unsigned short lVt[2][64 * 64];

  // Q fragment load with fused RoPE and folded softmax scale (0.125 * log2e)
  const float SC = 0.125f * 1.44269504f;
  bf16x8 qf[4];
  {
    int t = q0 + l31;
    const unsigned short* qp = qkv + (size_t)(b * 1024 + t) * 3072 + h * 64;
#pragma unroll
    for (int dk = 0; dk < 4; ++dk) {
      ushort8v q = *(const ushort8v*)(qp + dk * 16 + hi * 8);
      f32x4 c4 = *(const f32x4*)(cosb + t * 32 + dk * 8 + hi * 4);
      f32x4 s4 = *(const f32x4*)(sinb + t * 32 + dk * 8 + hi * 4);
      ushort8v o;
#pragma unroll
      for (int j = 0; j < 4; ++j) {
        float xr = b2f(q[2 * j]), xi = b2f(q[2 * j + 1]);
        o[2 * j]     = f2b((xr * c4[j] - xi * s4[j]) * SC);
        o[2 * j + 1] = f2b((xr * s4[j] + xi * c4[j]) * SC);
      }
      qf[dk] = __builtin_bit_cast(bf16x8, o);
    }
  }

  const unsigned short* kg = qkv + (size_t)(b * 1024) * 3072 + 2048 + kvh * 64;
  const unsigned short* vg = vt + (size_t)(b * 8 + kvh) * 64 * 1024;

  // 256-thread staging: 512 16B-chunks each for K and V; chunk c = tid + 256*i;
  // dest byte = c*16 (linear per wave: base + lane*16), src col pre-swizzled.
  auto stage = [&](int kvb, int bi) {
#pragma unroll
    for (int i = 0; i < 2; ++i) {
      int c = tid + 256 * i;
      int row = c >> 3;
      int colb = (c & 7) * 16;
      int cb = colb ^ ((row & 7) << 4);
      async16(kg + (size_t)(kvb + row) * 3072 + (cb >> 1), (char*)lK[bi] + c * 16);
      async16(vg + (size_t)row * 1024 + kvb + (cb >> 1), (char*)lVt[bi] + c * 16);
    }
  };

  f32x16 oacc[2] = {};
  float m2 = -3e38f, l_run = 0.f;

  auto chunk64 = [&](int cur, int ckvb, bool lastT) {
    f32x16 sd[2] = {};
    __builtin_amdgcn_s_setprio(1);
#pragma unroll
    for (int s = 0; s < 2; ++s) {
      const int krow = s * 32 + l31;
      const char* kr = (const char*)lK[cur] + krow * 128;
      const int swz = (krow & 7) << 4;
#pragma unroll
      for (int dk = 0; dk < 4; ++dk) {
        bf16x8 kf = *(const bf16x8*)(kr + ((dk * 32 + hi * 16) ^ swz));
        sd[s] = __builtin_amdgcn_mfma_f32_32x32x16_bf16(kf, qf[dk], sd[s], 0, 0, 0);
      }
    }
    __builtin_amdgcn_s_setprio(0);

    if (lastT) {
#pragma unroll
      for (int s = 0; s < 2; ++s)
#pragma unroll
        for (int r = 0; r < 16; ++r) {
          int kvg = ckvb + s * 32 + (r & 3) + 8 * (r >> 2) + 4 * hi;
          if (kvg > q0 + l31) sd[s][r] = -3e38f;
        }
    }
    float pm = sd[0][0];
#pragma unroll
    for (int s = 0; s < 2; ++s)
#pragma unroll
      for (int r = 0; r < 16; ++r) pm = fmaxf(pm, sd[s][r]);
    pm = fmaxf(pm, __shfl_xor(pm, 32));
    if (!__all(pm <= m2 + 11.0f)) {          // T13 defer-max (log2 domain)
      float mnew = fmaxf(m2, pm);
      float alpha = exp2f(m2 - mnew);
      m2 = mnew;
      l_run *= alpha;
#pragma unroll
      for (int db = 0; db < 2; ++db)
#pragma unroll
        for (int r = 0; r < 16; ++r) oacc[db][r] *= alpha;
    }
    float tsum = 0.f;
#pragma unroll
    for (int s = 0; s < 2; ++s)
#pragma unroll
      for (int r = 0; r < 16; ++r) { float p = exp2f(sd[s][r] - m2); sd[s][r] = p; tsum += p; }
    tsum += __shfl_xor(tsum, 32);
    l_run += tsum;

    bf16x8 pf[2][2];
#pragma unroll
    for (int s = 0; s < 2; ++s)
#pragma unroll
      for (int kc = 0; kc < 2; ++kc) {
        unsigned int cA = cvtpk(sd[s][8 * kc + 0], sd[s][8 * kc + 1]);
        unsigned int cB = cvtpk(sd[s][8 * kc + 4], sd[s][8 * kc + 5]);
        unsigned int cC = cvtpk(sd[s][8 * kc + 2], sd[s][8 * kc + 3]);
        unsigned int cD = cvtpk(sd[s][8 * kc + 6], sd[s][8 * kc + 7]);
        unsigned int xA = __shfl_xor(cA, 32), xB = __shfl_xor(cB, 32);
        unsigned int xC = __shfl_xor(cC, 32), xD = __shfl_xor(cD, 32);
        uint4v u;
        u[0] = hi ? xB : cA;
        u[1] = hi ? xD : cC;
        u[2] = hi ? cB : xA;
        u[3] = hi ? cD : xC;
        pf[s][kc] = __builtin_bit_cast(bf16x8, u);
      }

    __builtin_amdgcn_s_setprio(1);
#pragma unroll
    for (int db = 0; db < 2; ++db) {
      const int row = db * 32 + l31;
      const char* vr = (const char*)lVt[cur] + row * 128;
      const int vswz = (row & 7) << 4;
#pragma unroll
      for (int s = 0; s < 2; ++s)
#pragma unroll
        for (int kc = 0; kc < 2; ++kc) {
          bf16x8 vf = *(const bf16x8*)(vr + ((s * 64 + kc * 32 + hi * 16) ^ vswz));
          oacc[db] = __builtin_amdgcn_mfma_f32_32x32x16_bf16(vf, pf[s][kc], oacc[db], 0, 0, 0);
        }
    }
    __builtin_amdgcn_s_setprio(0);
  };

  stage(0, 0);
  __syncthreads();

  for (int j = 0; j < nt; ++j) {
    const int cur = j & 1;
    if (j + 1 < nt) stage((j + 1) * 64, cur ^ 1);   // issue-early (T14)
    chunk64(cur, j * 64, j == nt - 1);
    __syncthreads();   // drains prefetch + buffer handoff
  }

  // epilogue: O^T row r -> d = (r&3)+8*(r>>2)+4*hi, col = q = l31
  {
    float inv = 1.0f / l_run;
    unsigned short* orow = ob + (size_t)(b * 1024 + q0 + l31) * 2048 + h * 64;
#pragma unroll
    for (int db = 0; db < 2; ++db)
#pragma unroll
      for (int g = 0; g < 4; ++g) {
        int d0 = db * 32 + 8 * g + 4 * hi;
        ushort4v o;
#pragma unroll
        for (int j = 0; j < 4; ++j) o[j] = f2b(oacc[db][4 * g + j] * inv);
        *(ushort4v*)(orow + d0) = o;
      }
  }
}

extern "C" void kernel_launch(void* const* d_in, const int* in_sizes, int n_in,
                              void* d_out, int out_size, void* d_ws, size_t ws_size,
                              hipStream_t stream) {
  const float* input = (const float*)d_in[0];
  const float* fcos  = (const float*)d_in[1];
  const float* fsin  = (const float*)d_in[2];
  const float* wq = (const float*)d_in[4];
  const float* wk = (const float*)d_in[5];
  const float* wv = (const float*)d_in[6];
  const float* wo = (const float*)d_in[7];
  float* out = (float*)d_out;

  unsigned short* xb   = (unsigned short*)d_ws;               // 4096 x 2048 (dead after gemm1)
  unsigned short* wqkv = xb + (size_t)4096 * 2048;            // 3072 x 2048
  unsigned short* wob  = wqkv + (size_t)3072 * 2048;          // 2048 x 2048
  unsigned short* qkv  = wob + (size_t)2048 * 2048;           // 4096 x 3072
  unsigned short* ob   = qkv + (size_t)4096 * 3072;           // 4096 x 2048
  unsigned short* vtb  = xb;                                  // 4*8*64*1024 (reuses xb)

  hipFuncSetAttribute((const void*)&gemmLT<false, 192>,
                      hipFuncAttributeMaxDynamicSharedMemorySize, 81920);
  hipFuncSetAttribute((const void*)&gemmLT<true, 128>,
                      hipFuncAttributeMaxDynamicSharedMemorySize, 65536);

  CvtArgs ca;
  ca.src[0] = input; ca.dst[0] = xb;                        ca.n[0] = (long)4096 * 2048;
  ca.src[1] = wq;    ca.dst[1] = wqkv;                      ca.n[1] = (long)2048 * 2048;
  ca.src[2] = wk;    ca.dst[2] = wqkv + (size_t)2048 * 2048; ca.n[2] = (long)512 * 2048;
  ca.src[3] = wv;    ca.dst[3] = wqkv + (size_t)2560 * 2048; ca.n[3] = (long)512 * 2048;
  ca.src[4] = wo;    ca.dst[4] = wob;                       ca.n[4] = (long)2048 * 2048;
  hipLaunchKernelGGL(cvt5_kernel, dim3(2048), dim3(256), 0, stream, ca);

  // fused QKV projection: qkv = xb @ wqkv^T  (M=4096, N=3072, K=2048), 2 blocks/CU
  hipLaunchKernelGGL((gemmLT<false, 192>), dim3(16, 32), dim3(512), 81920,
                     stream, xb, wqkv, (void*)qkv);

  // K-RoPE in place + V transpose
  hipLaunchKernelGGL(ropekv_kernel, dim3(16, 8, 4), dim3(256), 0, stream,
                     qkv, fcos, fsin, vtb);

  // flash attention (Q-RoPE fused, scale folded) -> ob (b,t,h,d) bf16
  hipLaunchKernelGGL(attn_kernel, dim3(32, 8, 4), dim3(256), 0, stream,
                     qkv, vtb, fcos, fsin, ob);

  // output projection: out = ob @ wob^T  (M=4096, N=2048, K=2048), fp32 out, 2 blocks/CU
  hipLaunchKernelGGL((gemmLT<true, 128>), dim3(16, 32), dim3(512), 65536,
                     stream, ob, wob, (void*)out);
}

// Round 16
// 175.143 us; speedup vs baseline: 1.0759x; 1.0759x over previous
//
#include <hip/hip_runtime.h>
#include <cstdint>

// ---- types ----
typedef __bf16 bf16x8 __attribute__((ext_vector_type(8)));
typedef float  f32x4  __attribute__((ext_vector_type(4)));
typedef float  f32x16 __attribute__((ext_vector_type(16)));
typedef float  float8v __attribute__((ext_vector_type(8)));
typedef unsigned short ushort8v __attribute__((ext_vector_type(8)));
typedef unsigned short ushort4v __attribute__((ext_vector_type(4)));
typedef unsigned int   uint4v   __attribute__((ext_vector_type(4)));

__device__ __forceinline__ unsigned short f2b(float f) {
  uint32_t u = __builtin_bit_cast(uint32_t, f);
  u += 0x7FFFu + ((u >> 16) & 1u);     // round-to-nearest-even
  return (unsigned short)(u >> 16);
}
__device__ __forceinline__ float b2f(unsigned short h) {
  uint32_t u = ((uint32_t)h) << 16;
  return __builtin_bit_cast(float, u);
}
__device__ __forceinline__ unsigned int cvtpk(float lo, float hi_) {
  unsigned int r;
  asm("v_cvt_pk_bf16_f32 %0, %1, %2" : "=v"(r) : "v"(lo), "v"(hi_));
  return r;
}

__device__ __forceinline__ void async16(const void* g, void* l) {
  __builtin_amdgcn_global_load_lds(
      (const __attribute__((address_space(1))) void*)g,
      (__attribute__((address_space(3))) void*)l, 16, 0, 0);
}

// s_waitcnt immediates (gfx9 encoding): vmcnt[3:0]|[15:14], expcnt[6:4], lgkmcnt[11:8]
#define WAITVM(N)  __builtin_amdgcn_s_waitcnt(0x0F70 | ((N) & 15))

// ---- fused fp32 -> bf16 convert, 5 segments in one launch ----
struct CvtArgs {
  const float* src[5];
  unsigned short* dst[5];
  long n[5];
};
__global__ void cvt5_kernel(CvtArgs a) {
  long base = (long)blockIdx.x * blockDim.x + threadIdx.x;
  long gstride = (long)gridDim.x * blockDim.x;
#pragma unroll 1
  for (int sg = 0; sg < 5; ++sg) {
    const float* s = a.src[sg];
    unsigned short* d = a.dst[sg];
    long n8 = a.n[sg] >> 3;
    for (long i = base; i < n8; i += gstride) {
      float8v f = *(const float8v*)(s + i * 8);
      ushort8v o;
#pragma unroll
      for (int j = 0; j < 8; ++j) o[j] = f2b(f[j]);
      *(ushort8v*)(d + i * 8) = o;
    }
  }
}

// ---- 2-blocks/CU GEMM: C[M][N] = A[M][K] * W[N][K]^T, K=2048, BM=128 ----
template<bool F32OUT, int BN>
__global__ __launch_bounds__(512, 4)
void gemmLT(const unsigned short* __restrict__ Ag, const unsigned short* __restrict__ Wg,
            void* __restrict__ Cp) {
  constexpr int K = 2048;
  constexpr int NF = BN / 64;
  constexpr int BL = NF;
  constexpr int VMS = 1 + BL;
  constexpr int ASLOT = 8192;
  constexpr int BSLOT = BN * 128;
  constexpr int N = 16 * BN;

  extern __shared__ char lds_c[];

  const int tid = threadIdx.x;
  const int wave = tid >> 6, lane = tid & 63;
  const int wm = wave >> 2, wn = wave & 3;
  const int lr = lane & 15, lg = lane >> 4;

  const int flat = blockIdx.y * 16 + blockIdx.x;
  const int swz = (flat & 7) * 64 + (flat >> 3);
  const int m0 = (swz >> 4) * 128, n0 = (swz & 15) * BN;

  const int laneSw = (lr >> 1) * 128 + (((((lr & 1) << 2) | lg) ^ (lr >> 1)) << 4);
  const int aoff = wm * 4096 + laneSw;

  int bByte[NF], bR7[NF];
#pragma unroll
  for (int ni = 0; ni < NF; ++ni) {
    int row = wn * (NF * 16) + ni * 16 + lr;
    bByte[ni] = row * 128;
    bR7[ni] = row & 7;
  }

  f32x4 acc[4][NF] = {};
  bf16x8 af[2], bf[NF];

  auto stA = [&](int slot, int s) {
    char* sl = lds_c + slot * ASLOT;
    const int kc = s * 32;
    int q = tid * 16;
    int R = q >> 7, g2L = ((q >> 4) & 7) ^ (R & 7);
    int row = R * 2 + (g2L >> 2), kg = g2L & 3;
    async16(Ag + (size_t)(m0 + row) * K + kc + kg * 8, sl + q);
  };
  auto stB = [&](int slot, int T) {
    char* sl = lds_c + 4 * ASLOT + slot * BSLOT;
    const int kc = T * 64;
#pragma unroll
    for (int j = 0; j < BL; ++j) {
      int q = (tid + 512 * j) * 16;
      int row = q >> 7, c = (q >> 4) & 7;
      async16(Wg + (size_t)(n0 + row) * K + kc + ((c ^ (row & 7)) * 8), sl + q);
    }
  };

#define PH(SA, SB, MH, KH, RDB, STG, VM)                                      \
  {                                                                           \
    const char* As_ = lds_c + (SA) * ASLOT;                                   \
    _Pragma("unroll") for (int mi = 0; mi < 2; ++mi)                          \
      af[mi] = *(const bf16x8*)(As_ + aoff + ((MH) * 2 + mi) * 1024);         \
    if (RDB) {                                                                \
      const char* Bs_ = lds_c + 4 * ASLOT + (SB) * BSLOT;                     \
      _Pragma("unroll") for (int ni = 0; ni < NF; ++ni)                       \
        bf[ni] = *(const bf16x8*)(Bs_ + bByte[ni] +                           \
                                  (((((KH) << 2) | lg) ^ bR7[ni]) << 4));     \
    }                                                                         \
    STG;                                                                      \
    if ((VM) >= 0) WAITVM(VM);                                                \
    __builtin_amdgcn_s_barrier();                                             \
    __builtin_amdgcn_s_setprio(1);                                            \
    _Pragma("unroll") for (int mi = 0; mi < 2; ++mi)                          \
      _Pragma("unroll") for (int ni = 0; ni < NF; ++ni)                       \
        acc[(MH) * 2 + mi][ni] = __builtin_amdgcn_mfma_f32_16x16x32_bf16(     \
            af[mi], bf[ni], acc[(MH) * 2 + mi][ni], 0, 0, 0);                 \
    __builtin_amdgcn_s_setprio(0);                                            \
    __builtin_amdgcn_s_barrier();                                             \
  }

  stB(0, 0); stA(0, 0); stA(1, 1); stB(1, 1); stA(2, 2);
  WAITVM(VMS);
  __builtin_amdgcn_s_barrier();

  for (int t2 = 0; t2 < 30; t2 += 2) {
    PH(0, 0, 0, 0, true,  stA(3, 2 * t2 + 3), -1);
    PH(0, 0, 1, 0, false, (void)0, -1);
    PH(1, 0, 0, 1, true,  stA(0, 2 * t2 + 4), -1);
    PH(1, 0, 1, 1, false, stB(0, t2 + 2), VMS);
    PH(2, 1, 0, 0, true,  stA(1, 2 * t2 + 5), -1);
    PH(2, 1, 1, 0, false, (void)0, -1);
    PH(3, 1, 0, 1, true,  stA(2, 2 * t2 + 6), -1);
    PH(3, 1, 1, 1, false, stB(1, t2 + 3), VMS);
  }
  PH(0, 0, 0, 0, true,  stA(3, 63), -1);
  PH(0, 0, 1, 0, false, (void)0, -1);
  PH(1, 0, 0, 1, true,  (void)0, -1);
  PH(1, 0, 1, 1, false, (void)0, 0);
  PH(2, 1, 0, 0, true,  (void)0, -1);
  PH(2, 1, 1, 0, false, (void)0, -1);
  PH(3, 1, 0, 1, true,  (void)0, -1);
  PH(3, 1, 1, 1, false, (void)0, -1);
#undef PH

#pragma unroll
  for (int mig = 0; mig < 4; ++mig) {
#pragma unroll
    for (int j = 0; j < 4; ++j) {
      int row = m0 + wm * 64 + mig * 16 + lg * 4 + j;
#pragma unroll
      for (int ni = 0; ni < NF; ++ni) {
        int col = n0 + wn * (NF * 16) + ni * 16 + lr;
        float v = acc[mig][ni][j];
        if (F32OUT) ((float*)Cp)[(size_t)row * N + col] = v;
        else        ((unsigned short*)Cp)[(size_t)row * N + col] = f2b(v);
      }
    }
  }
}

// ---- fused K-RoPE (in place) + V transpose -> vt[b][kvh][d=64][t=1024] ----
__global__ __launch_bounds__(256)
void ropekv_kernel(unsigned short* __restrict__ qkv,
                   const float* __restrict__ cosb, const float* __restrict__ sinb,
                   unsigned short* __restrict__ vt) {
  const int tt0 = blockIdx.x * 64;
  const int kvh = blockIdx.y;
  const int b   = blockIdx.z;
  const int tid = threadIdx.x;

  {
    int r = tid >> 2, c0 = (tid & 3) * 16;
    int t = tt0 + r;
    unsigned short* kp = qkv + (size_t)(b * 1024 + t) * 3072 + 2048 + kvh * 64 + c0;
    const float* cb = cosb + t * 32 + c0 / 2;
    const float* sb = sinb + t * 32 + c0 / 2;
    ushort8v x0 = *(const ushort8v*)kp;
    ushort8v x1 = *(const ushort8v*)(kp + 8);
    float8v c = *(const float8v*)cb;
    float8v s = *(const float8v*)sb;
    ushort8v o0, o1;
#pragma unroll
    for (int j = 0; j < 4; ++j) {
      float xr = b2f(x0[2 * j]), xi = b2f(x0[2 * j + 1]);
      o0[2 * j]     = f2b(xr * c[j] - xi * s[j]);
      o0[2 * j + 1] = f2b(xr * s[j] + xi * c[j]);
    }
#pragma unroll
    for (int j = 0; j < 4; ++j) {
      float xr = b2f(x1[2 * j]), xi = b2f(x1[2 * j + 1]);
      o1[2 * j]     = f2b(xr * c[4 + j] - xi * s[4 + j]);
      o1[2 * j + 1] = f2b(xr * s[4 + j] + xi * c[4 + j]);
    }
    *(ushort8v*)kp = o0;
    *(ushort8v*)(kp + 8) = o1;
  }

  __shared__ unsigned short lT[64 * 68];
#pragma unroll
  for (int i = 0; i < 2; ++i) {
    int r = i * 32 + (tid >> 3), c = (tid & 7) * 8;
    const unsigned short* src = qkv + (size_t)(b * 1024 + tt0 + r) * 3072 + 2560 + kvh * 64 + c;
    ushort8v v = *(const ushort8v*)src;
    ushort4v a, b4;
#pragma unroll
    for (int j = 0; j < 4; ++j) { a[j] = v[j]; b4[j] = v[j + 4]; }
    *(ushort4v*)&lT[r * 68 + c]     = a;
    *(ushort4v*)&lT[r * 68 + c + 4] = b4;
  }
  __syncthreads();
#pragma unroll
  for (int i = 0; i < 2; ++i) {
    int d = tid & 63;
    int tt = i * 4 + (tid >> 6);
    ushort8v o;
#pragma unroll
    for (int j = 0; j < 8; ++j) o[j] = lT[(tt * 8 + j) * 68 + d];
    *(ushort8v*)&vt[((size_t)((b * 8 + kvh) * 64 + d)) * 1024 + tt0 + tt * 8] = o;
  }
}

// ---- flash attention: ONE q-tile per block, 4 waves = 4 heads, KVBLK=64 ----
// grid (32,8,4) XCD-swizzled, 256 threads. All waves share nt = qt/2+1 ->
// zero intra-block wave idling; 1024 variable-length blocks pack onto 256 CUs
// at 4 blocks/CU (LDS 32KB x 4 = 128KB; VGPR cap 128 -> NO spill; r15's
// (256,5) capped VGPR at 48 and spilled ~33MB of scratch per dispatch).
__global__ __launch_bounds__(256, 4)
void attn_kernel(const unsigned short* __restrict__ qkv, const unsigned short* __restrict__ vt,
                 const float* __restrict__ cosb, const float* __restrict__ sinb,
                 unsigned short* __restrict__ ob) {
  // chunked XCD swizzle over 1024 blocks (cpx=128): 4 (b,kvh) streams per XCD
  const int flat = (blockIdx.z * 8 + blockIdx.y) * 32 + blockIdx.x;
  const int swzb = (flat & 7) * 128 + (flat >> 3);
  const int qt = swzb & 31, kvh = (swzb >> 5) & 7, b = swzb >> 8;

  const int tid = threadIdx.x, wave = tid >> 6, lane = tid & 63;
  const int l31 = lane & 31, hi = lane >> 5;
  const int h = kvh * 4 + wave;

  const int q0 = qt * 32;
  const int nt = qt / 2 + 1;                         // KVBLK=64 tiles

  __shared__ unsigned short lK[2][64 * 64];
  __shared__ unsigned short lVt[2][64 * 64];

  // Q fragment load with fused RoPE and folded softmax scale (0.125 * log2e)
  const float SC = 0.125f * 1.44269504f;
  bf16x8 qf[4];
  {
    int t = q0 + l31;
    const unsigned short* qp = qkv + (size_t)(b * 1024 + t) * 3072 + h * 64;
#pragma unroll
    for (int dk = 0; dk < 4; ++dk) {
      ushort8v q = *(const ushort8v*)(qp + dk * 16 + hi * 8);
      f32x4 c4 = *(const f32x4*)(cosb + t * 32 + dk * 8 + hi * 4);
      f32x4 s4 = *(const f32x4*)(sinb + t * 32 + dk * 8 + hi * 4);
      ushort8v o;
#pragma unroll
      for (int j = 0; j < 4; ++j) {
        float xr = b2f(q[2 * j]), xi = b2f(q[2 * j + 1]);
        o[2 * j]     = f2b((xr * c4[j] - xi * s4[j]) * SC);
        o[2 * j + 1] = f2b((xr * s4[j] + xi * c4[j]) * SC);
      }
      qf[dk] = __builtin_bit_cast(bf16x8, o);
    }
  }

  const unsigned short* kg = qkv + (size_t)(b * 1024) * 3072 + 2048 + kvh * 64;
  const unsigned short* vg = vt + (size_t)(b * 8 + kvh) * 64 * 1024;

  // 256-thread staging: 512 16B-chunks each for K and V; chunk c = tid + 256*i;
  // dest byte = c*16 (linear per wave: base + lane*16), src col pre-swizzled.
  auto stage = [&](int kvb, int bi) {
#pragma unroll
    for (int i = 0; i < 2; ++i) {
      int c = tid + 256 * i;
      int row = c >> 3;
      int colb = (c & 7) * 16;
      int cb = colb ^ ((row & 7) << 4);
      async16(kg + (size_t)(kvb + row) * 3072 + (cb >> 1), (char*)lK[bi] + c * 16);
      async16(vg + (size_t)row * 1024 + kvb + (cb >> 1), (char*)lVt[bi] + c * 16);
    }
  };

  f32x16 oacc[2] = {};
  float m2 = -3e38f, l_run = 0.f;

  auto chunk64 = [&](int cur, int ckvb, bool lastT) {
    f32x16 sd[2] = {};
    __builtin_amdgcn_s_setprio(1);
#pragma unroll
    for (int s = 0; s < 2; ++s) {
      const int krow = s * 32 + l31;
      const char* kr = (const char*)lK[cur] + krow * 128;
      const int swz = (krow & 7) << 4;
#pragma unroll
      for (int dk = 0; dk < 4; ++dk) {
        bf16x8 kf = *(const bf16x8*)(kr + ((dk * 32 + hi * 16) ^ swz));
        sd[s] = __builtin_amdgcn_mfma_f32_32x32x16_bf16(kf, qf[dk], sd[s], 0, 0, 0);
      }
    }
    __builtin_amdgcn_s_setprio(0);

    if (lastT) {
#pragma unroll
      for (int s = 0; s < 2; ++s)
#pragma unroll
        for (int r = 0; r < 16; ++r) {
          int kvg = ckvb + s * 32 + (r & 3) + 8 * (r >> 2) + 4 * hi;
          if (kvg > q0 + l31) sd[s][r] = -3e38f;
        }
    }
    float pm = sd[0][0];
#pragma unroll
    for (int s = 0; s < 2; ++s)
#pragma unroll
      for (int r = 0; r < 16; ++r) pm = fmaxf(pm, sd[s][r]);
    pm = fmaxf(pm, __shfl_xor(pm, 32));
    if (!__all(pm <= m2 + 11.0f)) {          // T13 defer-max (log2 domain)
      float mnew = fmaxf(m2, pm);
      float alpha = exp2f(m2 - mnew);
      m2 = mnew;
      l_run *= alpha;
#pragma unroll
      for (int db = 0; db < 2; ++db)
#pragma unroll
        for (int r = 0; r < 16; ++r) oacc[db][r] *= alpha;
    }
    float tsum = 0.f;
#pragma unroll
    for (int s = 0; s < 2; ++s)
#pragma unroll
      for (int r = 0; r < 16; ++r) { float p = exp2f(sd[s][r] - m2); sd[s][r] = p; tsum += p; }
    tsum += __shfl_xor(tsum, 32);
    l_run += tsum;

    bf16x8 pf[2][2];
#pragma unroll
    for (int s = 0; s < 2; ++s)
#pragma unroll
      for (int kc = 0; kc < 2; ++kc) {
        unsigned int cA = cvtpk(sd[s][8 * kc + 0], sd[s][8 * kc + 1]);
        unsigned int cB = cvtpk(sd[s][8 * kc + 4], sd[s][8 * kc + 5]);
        unsigned int cC = cvtpk(sd[s][8 * kc + 2], sd[s][8 * kc + 3]);
        unsigned int cD = cvtpk(sd[s][8 * kc + 6], sd[s][8 * kc + 7]);
        unsigned int xA = __shfl_xor(cA, 32), xB = __shfl_xor(cB, 32);
        unsigned int xC = __shfl_xor(cC, 32), xD = __shfl_xor(cD, 32);
        uint4v u;
        u[0] = hi ? xB : cA;
        u[1] = hi ? xD : cC;
        u[2] = hi ? cB : xA;
        u[3] = hi ? cD : xC;
        pf[s][kc] = __builtin_bit_cast(bf16x8, u);
      }

    __builtin_amdgcn_s_setprio(1);
#pragma unroll
    for (int db = 0; db < 2; ++db) {
      const int row = db * 32 + l31;
      const char* vr = (const char*)lVt[cur] + row * 128;
      const int vswz = (row & 7) << 4;
#pragma unroll
      for (int s = 0; s < 2; ++s)
#pragma unroll
        for (int kc = 0; kc < 2; ++kc) {
          bf16x8 vf = *(const bf16x8*)(vr + ((s * 64 + kc * 32 + hi * 16) ^ vswz));
          oacc[db] = __builtin_amdgcn_mfma_f32_32x32x16_bf16(vf, pf[s][kc], oacc[db], 0, 0, 0);
        }
    }
    __builtin_amdgcn_s_setprio(0);
  };

  stage(0, 0);
  __syncthreads();

  for (int j = 0; j < nt; ++j) {
    const int cur = j & 1;
    if (j + 1 < nt) stage((j + 1) * 64, cur ^ 1);   // issue-early (T14)
    chunk64(cur, j * 64, j == nt - 1);
    __syncthreads();   // drains prefetch + buffer handoff
  }

  // epilogue: O^T row r -> d = (r&3)+8*(r>>2)+4*hi, col = q = l31
  {
    float inv = 1.0f / l_run;
    unsigned short* orow = ob + (size_t)(b * 1024 + q0 + l31) * 2048 + h * 64;
#pragma unroll
    for (int db = 0; db < 2; ++db)
#pragma unroll
      for (int g = 0; g < 4; ++g) {
        int d0 = db * 32 + 8 * g + 4 * hi;
        ushort4v o;
#pragma unroll
        for (int j = 0; j < 4; ++j) o[j] = f2b(oacc[db][4 * g + j] * inv);
        *(ushort4v*)(orow + d0) = o;
      }
  }
}

extern "C" void kernel_launch(void* const* d_in, const int* in_sizes, int n_in,
                              void* d_out, int out_size, void* d_ws, size_t ws_size,
                              hipStream_t stream) {
  const float* input = (const float*)d_in[0];
  const float* fcos  = (const float*)d_in[1];
  const float* fsin  = (const float*)d_in[2];
  const float* wq = (const float*)d_in[4];
  const float* wk = (const float*)d_in[5];
  const float* wv = (const float*)d_in[6];
  const float* wo = (const float*)d_in[7];
  float* out = (float*)d_out;

  unsigned short* xb   = (unsigned short*)d_ws;               // 4096 x 2048 (dead after gemm1)
  unsigned short* wqkv = xb + (size_t)4096 * 2048;            // 3072 x 2048
  unsigned short* wob  = wqkv + (size_t)3072 * 2048;          // 2048 x 2048
  unsigned short* qkv  = wob + (size_t)2048 * 2048;           // 4096 x 3072
  unsigned short* ob   = qkv + (size_t)4096 * 3072;           // 4096 x 2048
  unsigned short* vtb  = xb;                                  // 4*8*64*1024 (reuses xb)

  hipFuncSetAttribute((const void*)&gemmLT<false, 192>,
                      hipFuncAttributeMaxDynamicSharedMemorySize, 81920);
  hipFuncSetAttribute((const void*)&gemmLT<true, 128>,
                      hipFuncAttributeMaxDynamicSharedMemorySize, 65536);

  CvtArgs ca;
  ca.src[0] = input; ca.dst[0] = xb;                        ca.n[0] = (long)4096 * 2048;
  ca.src[1] = wq;    ca.dst[1] = wqkv;                      ca.n[1] = (long)2048 * 2048;
  ca.src[2] = wk;    ca.dst[2] = wqkv + (size_t)2048 * 2048; ca.n[2] = (long)512 * 2048;
  ca.src[3] = wv;    ca.dst[3] = wqkv + (size_t)2560 * 2048; ca.n[3] = (long)512 * 2048;
  ca.src[4] = wo;    ca.dst[4] = wob;                       ca.n[4] = (long)2048 * 2048;
  hipLaunchKernelGGL(cvt5_kernel, dim3(2048), dim3(256), 0, stream, ca);

  // fused QKV projection: qkv = xb @ wqkv^T  (M=4096, N=3072, K=2048), 2 blocks/CU
  hipLaunchKernelGGL((gemmLT<false, 192>), dim3(16, 32), dim3(512), 81920,
                     stream, xb, wqkv, (void*)qkv);

  // K-RoPE in place + V transpose
  hipLaunchKernelGGL(ropekv_kernel, dim3(16, 8, 4), dim3(256), 0, stream,
                     qkv, fcos, fsin, vtb);

  // flash attention (Q-RoPE fused, scale folded) -> ob (b,t,h,d) bf16
  hipLaunchKernelGGL(attn_kernel, dim3(32, 8, 4), dim3(256), 0, stream,
                     qkv, vtb, fcos, fsin, ob);

  // output projection: out = ob @ wob^T  (M=4096, N=2048, K=2048), fp32 out, 2 blocks/CU
  hipLaunchKernelGGL((gemmLT<true, 128>), dim3(16, 32), dim3(512), 65536,
                     stream, ob, wob, (void*)out);
}

// Round 17
// 158.123 us; speedup vs baseline: 1.1917x; 1.1076x over previous
//
#include <hip/hip_runtime.h>
#include <cstdint>

// ---- types ----
typedef __bf16 bf16x8 __attribute__((ext_vector_type(8)));
typedef float  f32x4  __attribute__((ext_vector_type(4)));
typedef float  f32x16 __attribute__((ext_vector_type(16)));
typedef float  float8v __attribute__((ext_vector_type(8)));
typedef unsigned short ushort8v __attribute__((ext_vector_type(8)));
typedef unsigned short ushort4v __attribute__((ext_vector_type(4)));
typedef unsigned int   uint4v   __attribute__((ext_vector_type(4)));

__device__ __forceinline__ unsigned short f2b(float f) {
  uint32_t u = __builtin_bit_cast(uint32_t, f);
  u += 0x7FFFu + ((u >> 16) & 1u);     // round-to-nearest-even
  return (unsigned short)(u >> 16);
}
__device__ __forceinline__ float b2f(unsigned short h) {
  uint32_t u = ((uint32_t)h) << 16;
  return __builtin_bit_cast(float, u);
}
__device__ __forceinline__ unsigned int cvtpk(float lo, float hi_) {
  unsigned int r;
  asm("v_cvt_pk_bf16_f32 %0, %1, %2" : "=v"(r) : "v"(lo), "v"(hi_));
  return r;
}

__device__ __forceinline__ void async16(const void* g, void* l) {
  __builtin_amdgcn_global_load_lds(
      (const __attribute__((address_space(1))) void*)g,
      (__attribute__((address_space(3))) void*)l, 16, 0, 0);
}

// s_waitcnt immediates (gfx9 encoding): vmcnt[3:0]|[15:14], expcnt[6:4], lgkmcnt[11:8]
#define WAITVM(N)  __builtin_amdgcn_s_waitcnt(0x0F70 | ((N) & 15))

// ---- fused fp32 -> bf16 convert, 5 segments in one launch ----
struct CvtArgs {
  const float* src[5];
  unsigned short* dst[5];
  long n[5];
};
__global__ void cvt5_kernel(CvtArgs a) {
  long base = (long)blockIdx.x * blockDim.x + threadIdx.x;
  long gstride = (long)gridDim.x * blockDim.x;
#pragma unroll 1
  for (int sg = 0; sg < 5; ++sg) {
    const float* s = a.src[sg];
    unsigned short* d = a.dst[sg];
    long n8 = a.n[sg] >> 3;
    for (long i = base; i < n8; i += gstride) {
      float8v f = *(const float8v*)(s + i * 8);
      ushort8v o;
#pragma unroll
      for (int j = 0; j < 8; ++j) o[j] = f2b(f[j]);
      *(ushort8v*)(d + i * 8) = o;
    }
  }
}

// ---- 2-blocks/CU GEMM: C[M][N] = A[M][K] * W[N][K]^T, K=2048, BM=128 ----
template<bool F32OUT, int BN>
__global__ __launch_bounds__(512, 4)
void gemmLT(const unsigned short* __restrict__ Ag, const unsigned short* __restrict__ Wg,
            void* __restrict__ Cp) {
  constexpr int K = 2048;
  constexpr int NF = BN / 64;
  constexpr int BL = NF;
  constexpr int VMS = 1 + BL;
  constexpr int ASLOT = 8192;
  constexpr int BSLOT = BN * 128;
  constexpr int N = 16 * BN;

  extern __shared__ char lds_c[];

  const int tid = threadIdx.x;
  const int wave = tid >> 6, lane = tid & 63;
  const int wm = wave >> 2, wn = wave & 3;
  const int lr = lane & 15, lg = lane >> 4;

  const int flat = blockIdx.y * 16 + blockIdx.x;
  const int swz = (flat & 7) * 64 + (flat >> 3);
  const int m0 = (swz >> 4) * 128, n0 = (swz & 15) * BN;

  const int laneSw = (lr >> 1) * 128 + (((((lr & 1) << 2) | lg) ^ (lr >> 1)) << 4);
  const int aoff = wm * 4096 + laneSw;

  int bByte[NF], bR7[NF];
#pragma unroll
  for (int ni = 0; ni < NF; ++ni) {
    int row = wn * (NF * 16) + ni * 16 + lr;
    bByte[ni] = row * 128;
    bR7[ni] = row & 7;
  }

  f32x4 acc[4][NF] = {};
  bf16x8 af[2], bf[NF];

  auto stA = [&](int slot, int s) {
    char* sl = lds_c + slot * ASLOT;
    const int kc = s * 32;
    int q = tid * 16;
    int R = q >> 7, g2L = ((q >> 4) & 7) ^ (R & 7);
    int row = R * 2 + (g2L >> 2), kg = g2L & 3;
    async16(Ag + (size_t)(m0 + row) * K + kc + kg * 8, sl + q);
  };
  auto stB = [&](int slot, int T) {
    char* sl = lds_c + 4 * ASLOT + slot * BSLOT;
    const int kc = T * 64;
#pragma unroll
    for (int j = 0; j < BL; ++j) {
      int q = (tid + 512 * j) * 16;
      int row = q >> 7, c = (q >> 4) & 7;
      async16(Wg + (size_t)(n0 + row) * K + kc + ((c ^ (row & 7)) * 8), sl + q);
    }
  };

#define PH(SA, SB, MH, KH, RDB, STG, VM)                                      \
  {                                                                           \
    const char* As_ = lds_c + (SA) * ASLOT;                                   \
    _Pragma("unroll") for (int mi = 0; mi < 2; ++mi)                          \
      af[mi] = *(const bf16x8*)(As_ + aoff + ((MH) * 2 + mi) * 1024);         \
    if (RDB) {                                                                \
      const char* Bs_ = lds_c + 4 * ASLOT + (SB) * BSLOT;                     \
      _Pragma("unroll") for (int ni = 0; ni < NF; ++ni)                       \
        bf[ni] = *(const bf16x8*)(Bs_ + bByte[ni] +                           \
                                  (((((KH) << 2) | lg) ^ bR7[ni]) << 4));     \
    }                                                                         \
    STG;                                                                      \
    if ((VM) >= 0) WAITVM(VM);                                                \
    __builtin_amdgcn_s_barrier();                                             \
    __builtin_amdgcn_s_setprio(1);                                            \
    _Pragma("unroll") for (int mi = 0; mi < 2; ++mi)                          \
      _Pragma("unroll") for (int ni = 0; ni < NF; ++ni)                       \
        acc[(MH) * 2 + mi][ni] = __builtin_amdgcn_mfma_f32_16x16x32_bf16(     \
            af[mi], bf[ni], acc[(MH) * 2 + mi][ni], 0, 0, 0);                 \
    __builtin_amdgcn_s_setprio(0);                                            \
    __builtin_amdgcn_s_barrier();                                             \
  }

  stB(0, 0); stA(0, 0); stA(1, 1); stB(1, 1); stA(2, 2);
  WAITVM(VMS);
  __builtin_amdgcn_s_barrier();

  for (int t2 = 0; t2 < 30; t2 += 2) {
    PH(0, 0, 0, 0, true,  stA(3, 2 * t2 + 3), -1);
    PH(0, 0, 1, 0, false, (void)0, -1);
    PH(1, 0, 0, 1, true,  stA(0, 2 * t2 + 4), -1);
    PH(1, 0, 1, 1, false, stB(0, t2 + 2), VMS);
    PH(2, 1, 0, 0, true,  stA(1, 2 * t2 + 5), -1);
    PH(2, 1, 1, 0, false, (void)0, -1);
    PH(3, 1, 0, 1, true,  stA(2, 2 * t2 + 6), -1);
    PH(3, 1, 1, 1, false, stB(1, t2 + 3), VMS);
  }
  PH(0, 0, 0, 0, true,  stA(3, 63), -1);
  PH(0, 0, 1, 0, false, (void)0, -1);
  PH(1, 0, 0, 1, true,  (void)0, -1);
  PH(1, 0, 1, 1, false, (void)0, 0);
  PH(2, 1, 0, 0, true,  (void)0, -1);
  PH(2, 1, 1, 0, false, (void)0, -1);
  PH(3, 1, 0, 1, true,  (void)0, -1);
  PH(3, 1, 1, 1, false, (void)0, -1);
#undef PH

#pragma unroll
  for (int mig = 0; mig < 4; ++mig) {
#pragma unroll
    for (int j = 0; j < 4; ++j) {
      int row = m0 + wm * 64 + mig * 16 + lg * 4 + j;
#pragma unroll
      for (int ni = 0; ni < NF; ++ni) {
        int col = n0 + wn * (NF * 16) + ni * 16 + lr;
        float v = acc[mig][ni][j];
        if (F32OUT) ((float*)Cp)[(size_t)row * N + col] = v;
        else        ((unsigned short*)Cp)[(size_t)row * N + col] = f2b(v);
      }
    }
  }
}

// ---- fused K-RoPE (in place) + V transpose -> vt[b][kvh][d=64][t=1024] ----
__global__ __launch_bounds__(256)
void ropekv_kernel(unsigned short* __restrict__ qkv,
                   const float* __restrict__ cosb, const float* __restrict__ sinb,
                   unsigned short* __restrict__ vt) {
  const int tt0 = blockIdx.x * 64;
  const int kvh = blockIdx.y;
  const int b   = blockIdx.z;
  const int tid = threadIdx.x;

  {
    int r = tid >> 2, c0 = (tid & 3) * 16;
    int t = tt0 + r;
    unsigned short* kp = qkv + (size_t)(b * 1024 + t) * 3072 + 2048 + kvh * 64 + c0;
    const float* cb = cosb + t * 32 + c0 / 2;
    const float* sb = sinb + t * 32 + c0 / 2;
    ushort8v x0 = *(const ushort8v*)kp;
    ushort8v x1 = *(const ushort8v*)(kp + 8);
    float8v c = *(const float8v*)cb;
    float8v s = *(const float8v*)sb;
    ushort8v o0, o1;
#pragma unroll
    for (int j = 0; j < 4; ++j) {
      float xr = b2f(x0[2 * j]), xi = b2f(x0[2 * j + 1]);
      o0[2 * j]     = f2b(xr * c[j] - xi * s[j]);
      o0[2 * j + 1] = f2b(xr * s[j] + xi * c[j]);
    }
#pragma unroll
    for (int j = 0; j < 4; ++j) {
      float xr = b2f(x1[2 * j]), xi = b2f(x1[2 * j + 1]);
      o1[2 * j]     = f2b(xr * c[4 + j] - xi * s[4 + j]);
      o1[2 * j + 1] = f2b(xr * s[4 + j] + xi * c[4 + j]);
    }
    *(ushort8v*)kp = o0;
    *(ushort8v*)(kp + 8) = o1;
  }

  __shared__ unsigned short lT[64 * 68];
#pragma unroll
  for (int i = 0; i < 2; ++i) {
    int r = i * 32 + (tid >> 3), c = (tid & 7) * 8;
    const unsigned short* src = qkv + (size_t)(b * 1024 + tt0 + r) * 3072 + 2560 + kvh * 64 + c;
    ushort8v v = *(const ushort8v*)src;
    ushort4v a, b4;
#pragma unroll
    for (int j = 0; j < 4; ++j) { a[j] = v[j]; b4[j] = v[j + 4]; }
    *(ushort4v*)&lT[r * 68 + c]     = a;
    *(ushort4v*)&lT[r * 68 + c + 4] = b4;
  }
  __syncthreads();
#pragma unroll
  for (int i = 0; i < 2; ++i) {
    int d = tid & 63;
    int tt = i * 4 + (tid >> 6);
    ushort8v o;
#pragma unroll
    for (int j = 0; j < 8; ++j) o[j] = lT[(tt * 8 + j) * 68 + d];
    *(ushort8v*)&vt[((size_t)((b * 8 + kvh) * 64 + d)) * 1024 + tt0 + tt * 8] = o;
  }
}

// ---- flash attention: 8 waves = {hi,lo} q-tiles x 4 heads, KVBLK=64 ----
// (r13/r14 version — best measured: 59.3 us, VGPR 60, no spill.)
// grid (16,8,4) XCD-swizzled, 512 threads. Waves 0-3: q-tile 31-bx (heads 0-3);
// waves 4-7: q-tile bx. Shared K/V staging (lo kv-range is a subset of hi's).
__global__ __launch_bounds__(512, 4)
void attn_kernel(const unsigned short* __restrict__ qkv, const unsigned short* __restrict__ vt,
                 const float* __restrict__ cosb, const float* __restrict__ sinb,
                 unsigned short* __restrict__ ob) {
  const int flat = (blockIdx.z * 8 + blockIdx.y) * 16 + blockIdx.x;
  const int swzb = (flat & 7) * 64 + (flat >> 3);
  const int bx = swzb & 15, kvh = (swzb >> 4) & 7, b = swzb >> 7;

  const int tid = threadIdx.x, wave = tid >> 6, lane = tid & 63;
  const int l31 = lane & 31, hi = lane >> 5;
  const int wq = wave & 3, wh = wave >> 2;          // wh: 0 = hi q-tile, 1 = lo
  const int h = kvh * 4 + wq;

  const int qth = 31 - bx, qtl = bx;
  const int nth = qth / 2 + 1, ntl = qtl / 2 + 1;   // KVBLK=64 tile counts
  const int q0 = (wh ? qtl : qth) * 32;
  const int nt = wh ? ntl : nth;

  __shared__ unsigned short lK[2][64 * 64];
  __shared__ unsigned short lVt[2][64 * 64];

  // Q fragment load with fused RoPE and folded softmax scale (0.125 * log2e)
  const float SC = 0.125f * 1.44269504f;
  bf16x8 qf[4];
  {
    int t = q0 + l31;
    const unsigned short* qp = qkv + (size_t)(b * 1024 + t) * 3072 + h * 64;
#pragma unroll
    for (int dk = 0; dk < 4; ++dk) {
      ushort8v q = *(const ushort8v*)(qp + dk * 16 + hi * 8);
      f32x4 c4 = *(const f32x4*)(cosb + t * 32 + dk * 8 + hi * 4);
      f32x4 s4 = *(const f32x4*)(sinb + t * 32 + dk * 8 + hi * 4);
      ushort8v o;
#pragma unroll
      for (int j = 0; j < 4; ++j) {
        float xr = b2f(q[2 * j]), xi = b2f(q[2 * j + 1]);
        o[2 * j]     = f2b((xr * c4[j] - xi * s4[j]) * SC);
        o[2 * j + 1] = f2b((xr * s4[j] + xi * c4[j]) * SC);
      }
      qf[dk] = __builtin_bit_cast(bf16x8, o);
    }
  }

  const unsigned short* kg = qkv + (size_t)(b * 1024) * 3072 + 2048 + kvh * 64;
  const unsigned short* vg = vt + (size_t)(b * 8 + kvh) * 64 * 1024;

  // 512-thread staging: K rows 0..63 (1 issue), Vt rows 0..63 (1 issue);
  // per-wave LDS dest is base + lane*16 (linear) as global_load_lds requires.
  auto stage = [&](int kvb, int bi) {
    const int sr  = tid >> 3;          // 0..63
    const int scb = (tid & 7) * 16;    // 0..112 byte
    {
      int cb = scb ^ ((sr & 7) << 4);
      async16(kg + (size_t)(kvb + sr) * 3072 + (cb >> 1), &lK[bi][sr * 64 + (scb >> 1)]);
    }
    {
      int cbv = scb ^ ((sr & 7) << 4);
      async16(vg + (size_t)sr * 1024 + kvb + (cbv >> 1), &lVt[bi][sr * 64 + (scb >> 1)]);
    }
  };

  f32x16 oacc[2] = {};
  float m2 = -3e38f, l_run = 0.f;

  auto chunk64 = [&](int cur, int ckvb, bool lastT) {
    f32x16 sd[2] = {};
    __builtin_amdgcn_s_setprio(1);
#pragma unroll
    for (int s = 0; s < 2; ++s) {
      const int krow = s * 32 + l31;
      const char* kr = (const char*)lK[cur] + krow * 128;
      const int swz = (krow & 7) << 4;
#pragma unroll
      for (int dk = 0; dk < 4; ++dk) {
        bf16x8 kf = *(const bf16x8*)(kr + ((dk * 32 + hi * 16) ^ swz));
        sd[s] = __builtin_amdgcn_mfma_f32_32x32x16_bf16(kf, qf[dk], sd[s], 0, 0, 0);
      }
    }
    __builtin_amdgcn_s_setprio(0);

    if (lastT) {
#pragma unroll
      for (int s = 0; s < 2; ++s)
#pragma unroll
        for (int r = 0; r < 16; ++r) {
          int kvg = ckvb + s * 32 + (r & 3) + 8 * (r >> 2) + 4 * hi;
          if (kvg > q0 + l31) sd[s][r] = -3e38f;
        }
    }
    float pm = sd[0][0];
#pragma unroll
    for (int s = 0; s < 2; ++s)
#pragma unroll
      for (int r = 0; r < 16; ++r) pm = fmaxf(pm, sd[s][r]);
    pm = fmaxf(pm, __shfl_xor(pm, 32));
    if (!__all(pm <= m2 + 11.0f)) {          // T13 defer-max (log2 domain)
      float mnew = fmaxf(m2, pm);
      float alpha = exp2f(m2 - mnew);
      m2 = mnew;
      l_run *= alpha;
#pragma unroll
      for (int db = 0; db < 2; ++db)
#pragma unroll
        for (int r = 0; r < 16; ++r) oacc[db][r] *= alpha;
    }
    float tsum = 0.f;
#pragma unroll
    for (int s = 0; s < 2; ++s)
#pragma unroll
      for (int r = 0; r < 16; ++r) { float p = exp2f(sd[s][r] - m2); sd[s][r] = p; tsum += p; }
    tsum += __shfl_xor(tsum, 32);
    l_run += tsum;

    bf16x8 pf[2][2];
#pragma unroll
    for (int s = 0; s < 2; ++s)
#pragma unroll
      for (int kc = 0; kc < 2; ++kc) {
        unsigned int cA = cvtpk(sd[s][8 * kc + 0], sd[s][8 * kc + 1]);
        unsigned int cB = cvtpk(sd[s][8 * kc + 4], sd[s][8 * kc + 5]);
        unsigned int cC = cvtpk(sd[s][8 * kc + 2], sd[s][8 * kc + 3]);
        unsigned int cD = cvtpk(sd[s][8 * kc + 6], sd[s][8 * kc + 7]);
        unsigned int xA = __shfl_xor(cA, 32), xB = __shfl_xor(cB, 32);
        unsigned int xC = __shfl_xor(cC, 32), xD = __shfl_xor(cD, 32);
        uint4v u;
        u[0] = hi ? xB : cA;
        u[1] = hi ? xD : cC;
        u[2] = hi ? cB : xA;
        u[3] = hi ? cD : xC;
        pf[s][kc] = __builtin_bit_cast(bf16x8, u);
      }

    __builtin_amdgcn_s_setprio(1);
#pragma unroll
    for (int db = 0; db < 2; ++db) {
      const int row = db * 32 + l31;
      const char* vr = (const char*)lVt[cur] + row * 128;
      const int vswz = (row & 7) << 4;
#pragma unroll
      for (int s = 0; s < 2; ++s)
#pragma unroll
        for (int kc = 0; kc < 2; ++kc) {
          bf16x8 vf = *(const bf16x8*)(vr + ((s * 64 + kc * 32 + hi * 16) ^ vswz));
          oacc[db] = __builtin_amdgcn_mfma_f32_32x32x16_bf16(vf, pf[s][kc], oacc[db], 0, 0, 0);
        }
    }
    __builtin_amdgcn_s_setprio(0);
  };

  stage(0, 0);
  __syncthreads();

  for (int j = 0; j < nth; ++j) {
    const int cur = j & 1;
    if (j + 1 < nth) stage((j + 1) * 64, cur ^ 1);   // issue-early (T14)
    if (j < nt) chunk64(cur, j * 64, j == nt - 1);   // wave-uniform
    __syncthreads();   // drains prefetch + buffer handoff
  }

  // epilogue: O^T row r -> d = (r&3)+8*(r>>2)+4*hi, col = q = l31
  {
    float inv = 1.0f / l_run;
    unsigned short* orow = ob + (size_t)(b * 1024 + q0 + l31) * 2048 + h * 64;
#pragma unroll
    for (int db = 0; db < 2; ++db)
#pragma unroll
      for (int g = 0; g < 4; ++g) {
        int d0 = db * 32 + 8 * g + 4 * hi;
        ushort4v o;
#pragma unroll
        for (int j = 0; j < 4; ++j) o[j] = f2b(oacc[db][4 * g + j] * inv);
        *(ushort4v*)(orow + d0) = o;
      }
  }
}

extern "C" void kernel_launch(void* const* d_in, const int* in_sizes, int n_in,
                              void* d_out, int out_size, void* d_ws, size_t ws_size,
                              hipStream_t stream) {
  const float* input = (const float*)d_in[0];
  const float* fcos  = (const float*)d_in[1];
  const float* fsin  = (const float*)d_in[2];
  const float* wq = (const float*)d_in[4];
  const float* wk = (const float*)d_in[5];
  const float* wv = (const float*)d_in[6];
  const float* wo = (const float*)d_in[7];
  float* out = (float*)d_out;

  unsigned short* xb   = (unsigned short*)d_ws;               // 4096 x 2048 (dead after gemm1)
  unsigned short* wqkv = xb + (size_t)4096 * 2048;            // 3072 x 2048
  unsigned short* wob  = wqkv + (size_t)3072 * 2048;          // 2048 x 2048
  unsigned short* qkv  = wob + (size_t)2048 * 2048;           // 4096 x 3072
  unsigned short* ob   = qkv + (size_t)4096 * 3072;           // 4096 x 2048
  unsigned short* vtb  = xb;                                  // 4*8*64*1024 (reuses xb)

  hipFuncSetAttribute((const void*)&gemmLT<false, 192>,
                      hipFuncAttributeMaxDynamicSharedMemorySize, 81920);
  hipFuncSetAttribute((const void*)&gemmLT<true, 128>,
                      hipFuncAttributeMaxDynamicSharedMemorySize, 65536);

  CvtArgs ca;
  ca.src[0] = input; ca.dst[0] = xb;                        ca.n[0] = (long)4096 * 2048;
  ca.src[1] = wq;    ca.dst[1] = wqkv;                      ca.n[1] = (long)2048 * 2048;
  ca.src[2] = wk;    ca.dst[2] = wqkv + (size_t)2048 * 2048; ca.n[2] = (long)512 * 2048;
  ca.src[3] = wv;    ca.dst[3] = wqkv + (size_t)2560 * 2048; ca.n[3] = (long)512 * 2048;
  ca.src[4] = wo;    ca.dst[4] = wob;                       ca.n[4] = (long)2048 * 2048;
  hipLaunchKernelGGL(cvt5_kernel, dim3(2048), dim3(256), 0, stream, ca);

  // fused QKV projection: qkv = xb @ wqkv^T  (M=4096, N=3072, K=2048), 2 blocks/CU
  hipLaunchKernelGGL((gemmLT<false, 192>), dim3(16, 32), dim3(512), 81920,
                     stream, xb, wqkv, (void*)qkv);

  // K-RoPE in place + V transpose
  hipLaunchKernelGGL(ropekv_kernel, dim3(16, 8, 4), dim3(256), 0, stream,
                     qkv, fcos, fsin, vtb);

  // flash attention (Q-RoPE fused, scale folded) -> ob (b,t,h,d) bf16
  hipLaunchKernelGGL(attn_kernel, dim3(16, 8, 4), dim3(512), 0, stream,
                     qkv, vtb, fcos, fsin, ob);

  // output projection: out = ob @ wob^T  (M=4096, N=2048, K=2048), fp32 out, 2 blocks/CU
  hipLaunchKernelGGL((gemmLT<true, 128>), dim3(16, 32), dim3(512), 65536,
                     stream, ob, wob, (void*)out);
}